// Round 11
// baseline (234.658 us; speedup 1.0000x reference)
//
#include <hip/hip_runtime.h>
#include <hip/hip_bf16.h>

#define T_TOK 1024
#define TOPK  2
#define NEXP  8
#define HDIM  2048
#define IDIM  768
#define MROW  384   // per-expert row capacity (mean 256, sd ~15)
#define KC    128   // K-chunk elems staged to LDS per barrier

typedef __attribute__((ext_vector_type(4))) float f32x4;
typedef __attribute__((ext_vector_type(8))) short bf16x8;
typedef __attribute__((ext_vector_type(8))) unsigned short u16x8;
typedef __attribute__((ext_vector_type(8))) __bf16 bfv8;

__device__ __forceinline__ bf16x8 cvt8(f32x4 v0, f32x4 v1) {
  bfv8 r;
#pragma unroll
  for (int j = 0; j < 4; ++j) { r[j] = (__bf16)v0[j]; r[4 + j] = (__bf16)v1[j]; }
  return __builtin_bit_cast(bf16x8, r);
}

// ---------------- workspace layout (bytes) ----------------
// cnt : int[8]                 @ 0
// tok : int[8*2048]            @ 64
// wl  : float[8*2048]          @ 65600
// inv : int[2048]              @ 131136
// xe  : ushort[8*384*2048]     @ 139328   (12.6 MB, expert-compacted bf16 x)
// hb  : ushort[8*384*768]      @ 12722240 (4.7 MB)

__global__ void k_gather(const int* __restrict__ idx, const float* __restrict__ wts,
                         int* __restrict__ cnt, int* __restrict__ tok,
                         float* __restrict__ wl, int* __restrict__ inv) {
  int g = blockIdx.x * 256 + threadIdx.x;   // pid = t*2+k
  int e = idx[g];
  float w = wts[g];
  int pos = atomicAdd(&cnt[e], 1);
  if (pos < 2048) { tok[e * 2048 + pos] = g; wl[e * 2048 + pos] = w; }
  inv[g] = (pos < MROW) ? (e * MROW + pos) : -1;
}

__global__ __launch_bounds__(256) void k_compact(const float* __restrict__ x,
                                                 const int* __restrict__ inv,
                                                 unsigned short* __restrict__ xe) {
  int pid = blockIdx.x;
  int iv = inv[pid];
  if (iv < 0) return;
  const float* src = x + (size_t)(pid >> 1) * HDIM;
  unsigned short* dst = xe + (size_t)iv * HDIM;
  int i = threadIdx.x * 8;
  f32x4 a = *(const f32x4*)(src + i);
  f32x4 b = *(const f32x4*)(src + i + 4);
  *(bf16x8*)(dst + i) = cvt8(a, b);
}

// ================= gate_up =================
// grid 8e x 12nb = 96 blocks, 1024 thr (16 waves = 8M x 2N). Full-M=384,
// block cols = 64 gate + 64 up. Wgu read EXACTLY ONCE (no M-tiling).
// B: f32 -> reg (issued 1 full chunk ahead) -> cvt -> swizzled LDS chunk
// [128 rows][KC], dbuf, ONE __syncthreads per chunk (16 total).
// A: register-direct from L2/L3-resident xe, depth-2 rolling prefetch.
// 48 MFMA per wave between barriers.
__global__ __launch_bounds__(1024) void k_gate_up(
    const unsigned short* __restrict__ xe, const float* __restrict__ Wgu,
    const int* __restrict__ cnt, const float* __restrict__ wl,
    unsigned short* __restrict__ hb)
{
  const int b = blockIdx.x;
  const int e = b & 7;            // XCD pin
  const int nb = b >> 3;          // 0..11
  const int col0 = nb * 64;
  int cc = cnt[e]; if (cc > MROW) cc = MROW;

  __shared__ unsigned short sB[2][128 * KC];
  __shared__ float sW[MROW];

  const int tid = threadIdx.x;
  const int lane = tid & 63, wid = tid >> 6;
  const int fl = lane & 15, q = lane >> 4;
  const int wm = (wid >> 1) * 48;      // wave row base (8 waves x 48 = 384)
  const int wn = (wid & 1) * 32;       // wave col base within 64

  if (tid < MROW) sW[tid] = (tid < cc) ? wl[e * 2048 + tid] : 0.f;

  // B staging: thread -> LDS row tid>>3 (0..127), k-part (tid&7)*16 floats
  const int srow = tid >> 3, skp = tid & 7;
  const int ocol = (srow < 64) ? (col0 + srow) : (IDIM + col0 + (srow - 64));
  const float* bSrc = Wgu + ((size_t)e * 2 * IDIM + ocol) * HDIM + skp * 16;
  const unsigned int wOff0 = srow * KC + (((skp * 2 + 0) ^ (srow & 7)) * 8);
  const unsigned int wOff1 = srow * KC + (((skp * 2 + 1) ^ (srow & 7)) * 8);

  // A stream: rows wm + rf*16 + fl, k chunk q*8
  const unsigned short* xeE = xe + (size_t)e * MROW * HDIM;
  const unsigned short* aB0 = xeE + (size_t)(wm + 0 * 16 + fl) * HDIM + q * 8;
  const unsigned short* aB1 = xeE + (size_t)(wm + 1 * 16 + fl) * HDIM + q * 8;
  const unsigned short* aB2 = xeE + (size_t)(wm + 2 * 16 + fl) * HDIM + q * 8;

  f32x4 accg[3][2], accu[3][2];
#pragma unroll
  for (int rf = 0; rf < 3; ++rf)
#pragma unroll
    for (int cf = 0; cf < 2; ++cf) {
      accg[rf][cf] = f32x4{0.f, 0.f, 0.f, 0.f};
      accu[rf][cf] = f32x4{0.f, 0.f, 0.f, 0.f};
    }

  bf16x8 A0[3], A1[3];
  f32x4 br0, br1, br2, br3;

  const int NCH = HDIM / KC;      // 16 chunks, 64 k32-steps total
  const int NST = HDIM / 32;      // 64

  auto STEP = [&](int s, int g, bf16x8 (&AS)[3], const unsigned short* B) {
    const int rg0 = wn + fl,      rg1 = wn + 16 + fl;
    const int ru0 = 64 + wn + fl, ru1 = 64 + wn + 16 + fl;
    bf16x8 bg0 = *(const bf16x8*)&B[rg0 * KC + (((s * 4 + q) ^ (rg0 & 7)) * 8)];
    bf16x8 bg1 = *(const bf16x8*)&B[rg1 * KC + (((s * 4 + q) ^ (rg1 & 7)) * 8)];
    bf16x8 bu0 = *(const bf16x8*)&B[ru0 * KC + (((s * 4 + q) ^ (ru0 & 7)) * 8)];
    bf16x8 bu1 = *(const bf16x8*)&B[ru1 * KC + (((s * 4 + q) ^ (ru1 & 7)) * 8)];
#pragma unroll
    for (int rf = 0; rf < 3; ++rf) {
      accg[rf][0] = __builtin_amdgcn_mfma_f32_16x16x32_bf16(AS[rf], bg0, accg[rf][0], 0, 0, 0);
      accg[rf][1] = __builtin_amdgcn_mfma_f32_16x16x32_bf16(AS[rf], bg1, accg[rf][1], 0, 0, 0);
      accu[rf][0] = __builtin_amdgcn_mfma_f32_16x16x32_bf16(AS[rf], bu0, accu[rf][0], 0, 0, 0);
      accu[rf][1] = __builtin_amdgcn_mfma_f32_16x16x32_bf16(AS[rf], bu1, accu[rf][1], 0, 0, 0);
    }
    if (g + 2 < NST) {
      AS[0] = *(const bf16x8*)(aB0 + (g + 2) * 32);
      AS[1] = *(const bf16x8*)(aB1 + (g + 2) * 32);
      AS[2] = *(const bf16x8*)(aB2 + (g + 2) * 32);
    }
  };

  // prologue: B chunk0 -> regs; A steps 0,1 -> regs; write chunk0; sync; issue B1
  br0 = *(const f32x4*)(bSrc);      br1 = *(const f32x4*)(bSrc + 4);
  br2 = *(const f32x4*)(bSrc + 8);  br3 = *(const f32x4*)(bSrc + 12);
  A0[0] = *(const bf16x8*)(aB0); A0[1] = *(const bf16x8*)(aB1); A0[2] = *(const bf16x8*)(aB2);
  A1[0] = *(const bf16x8*)(aB0 + 32); A1[1] = *(const bf16x8*)(aB1 + 32); A1[2] = *(const bf16x8*)(aB2 + 32);
  *(bf16x8*)&sB[0][wOff0] = cvt8(br0, br1);
  *(bf16x8*)&sB[0][wOff1] = cvt8(br2, br3);
  __syncthreads();
  {
    const float* p = bSrc + KC;
    br0 = *(const f32x4*)(p);     br1 = *(const f32x4*)(p + 4);
    br2 = *(const f32x4*)(p + 8); br3 = *(const f32x4*)(p + 12);
  }

#pragma unroll 1
  for (int c = 0; c < NCH; ++c) {
    const unsigned short* B = sB[c & 1];
    STEP(0, c * 4 + 0, A0, B);
    STEP(1, c * 4 + 1, A1, B);
    STEP(2, c * 4 + 2, A0, B);
    STEP(3, c * 4 + 3, A1, B);
    if (c + 1 < NCH) {
      unsigned short* W = sB[(c + 1) & 1];
      *(bf16x8*)&W[wOff0] = cvt8(br0, br1);
      *(bf16x8*)&W[wOff1] = cvt8(br2, br3);
      __syncthreads();
      if (c + 2 < NCH) {
        const float* p = bSrc + (size_t)(c + 2) * KC;
        br0 = *(const f32x4*)(p);     br1 = *(const f32x4*)(p + 4);
        br2 = *(const f32x4*)(p + 8); br3 = *(const f32x4*)(p + 12);
      }
    }
  }

  unsigned short* hbE = hb + (size_t)e * MROW * IDIM;
  const int q4 = q * 4;
#pragma unroll
  for (int rf = 0; rf < 3; ++rf)
#pragma unroll
    for (int cf = 0; cf < 2; ++cf)
#pragma unroll
      for (int v = 0; v < 4; ++v) {
        int row = wm + rf * 16 + q4 + v;
        if (row < cc) {
          float g = accg[rf][cf][v], u = accu[rf][cf][v];
          float s = g / (1.f + __expf(-g));
          float h = s * u * sW[row];
          hbE[(size_t)row * IDIM + col0 + wn + cf * 16 + fl] =
              __builtin_bit_cast(unsigned short, (__bf16)h);
        }
      }
}

// ================= down =================
// grid 8e x 16nb = 128 blocks, 1024 thr. Full-M=384, N=128 h-cols.
// Wd read EXACTLY ONCE. Same chunked-B / reg-A structure, 6 chunks (K=768).
__global__ __launch_bounds__(1024) void k_down(
    const unsigned short* __restrict__ hb, const float* __restrict__ Wd,
    const int* __restrict__ cnt, const int* __restrict__ tok,
    float* __restrict__ out)
{
  const int b = blockIdx.x;
  const int e = b & 7;
  const int nb = b >> 3;          // 0..15
  const int col0 = nb * 128;
  int cc = cnt[e]; if (cc > MROW) cc = MROW;

  __shared__ unsigned short sB[2][128 * KC];
  __shared__ int sTok[MROW];

  const int tid = threadIdx.x;
  const int lane = tid & 63, wid = tid >> 6;
  const int fl = lane & 15, q = lane >> 4;
  const int wm = (wid >> 1) * 48;
  const int wn = (wid & 1) * 64;

  if (tid < MROW) sTok[tid] = (tid < cc) ? (tok[e * 2048 + tid] >> 1) : 0;

  const int srow = tid >> 3, skp = tid & 7;
  const float* bSrc = Wd + ((size_t)e * HDIM + col0 + srow) * IDIM + skp * 16;
  const unsigned int wOff0 = srow * KC + (((skp * 2 + 0) ^ (srow & 7)) * 8);
  const unsigned int wOff1 = srow * KC + (((skp * 2 + 1) ^ (srow & 7)) * 8);

  const unsigned short* hbE = hb + (size_t)e * MROW * IDIM;
  const unsigned short* aB0 = hbE + (size_t)(wm + 0 * 16 + fl) * IDIM + q * 8;
  const unsigned short* aB1 = hbE + (size_t)(wm + 1 * 16 + fl) * IDIM + q * 8;
  const unsigned short* aB2 = hbE + (size_t)(wm + 2 * 16 + fl) * IDIM + q * 8;

  f32x4 acc[3][4];
#pragma unroll
  for (int rf = 0; rf < 3; ++rf)
#pragma unroll
    for (int cf = 0; cf < 4; ++cf) acc[rf][cf] = f32x4{0.f, 0.f, 0.f, 0.f};

  bf16x8 A0[3], A1[3];
  f32x4 br0, br1, br2, br3;

  const int NCH = IDIM / KC;   // 6 chunks
  const int NST = IDIM / 32;   // 24 steps

  auto STEP = [&](int s, int g, bf16x8 (&AS)[3], const unsigned short* B) {
    bf16x8 bb[4];
#pragma unroll
    for (int cf = 0; cf < 4; ++cf) {
      int rn = wn + cf * 16 + fl;
      bb[cf] = *(const bf16x8*)&B[rn * KC + (((s * 4 + q) ^ (rn & 7)) * 8)];
    }
#pragma unroll
    for (int rf = 0; rf < 3; ++rf)
#pragma unroll
      for (int cf = 0; cf < 4; ++cf)
        acc[rf][cf] = __builtin_amdgcn_mfma_f32_16x16x32_bf16(AS[rf], bb[cf], acc[rf][cf], 0, 0, 0);
    if (g + 2 < NST) {
      AS[0] = *(const bf16x8*)(aB0 + (g + 2) * 32);
      AS[1] = *(const bf16x8*)(aB1 + (g + 2) * 32);
      AS[2] = *(const bf16x8*)(aB2 + (g + 2) * 32);
    }
  };

  br0 = *(const f32x4*)(bSrc);      br1 = *(const f32x4*)(bSrc + 4);
  br2 = *(const f32x4*)(bSrc + 8);  br3 = *(const f32x4*)(bSrc + 12);
  A0[0] = *(const bf16x8*)(aB0); A0[1] = *(const bf16x8*)(aB1); A0[2] = *(const bf16x8*)(aB2);
  A1[0] = *(const bf16x8*)(aB0 + 32); A1[1] = *(const bf16x8*)(aB1 + 32); A1[2] = *(const bf16x8*)(aB2 + 32);
  *(bf16x8*)&sB[0][wOff0] = cvt8(br0, br1);
  *(bf16x8*)&sB[0][wOff1] = cvt8(br2, br3);
  __syncthreads();
  {
    const float* p = bSrc + KC;
    br0 = *(const f32x4*)(p);     br1 = *(const f32x4*)(p + 4);
    br2 = *(const f32x4*)(p + 8); br3 = *(const f32x4*)(p + 12);
  }

#pragma unroll 1
  for (int c = 0; c < NCH; ++c) {
    const unsigned short* B = sB[c & 1];
    STEP(0, c * 4 + 0, A0, B);
    STEP(1, c * 4 + 1, A1, B);
    STEP(2, c * 4 + 2, A0, B);
    STEP(3, c * 4 + 3, A1, B);
    if (c + 1 < NCH) {
      unsigned short* W = sB[(c + 1) & 1];
      *(bf16x8*)&W[wOff0] = cvt8(br0, br1);
      *(bf16x8*)&W[wOff1] = cvt8(br2, br3);
      __syncthreads();
      if (c + 2 < NCH) {
        const float* p = bSrc + (size_t)(c + 2) * KC;
        br0 = *(const f32x4*)(p);     br1 = *(const f32x4*)(p + 4);
        br2 = *(const f32x4*)(p + 8); br3 = *(const f32x4*)(p + 12);
      }
    }
  }

  const int q4 = q * 4;
#pragma unroll
  for (int rf = 0; rf < 3; ++rf)
#pragma unroll
    for (int cf = 0; cf < 4; ++cf)
#pragma unroll
      for (int v = 0; v < 4; ++v) {
        int row = wm + rf * 16 + q4 + v;
        if (row < cc) {
          int t = sTok[row];
          atomicAdd(out + (size_t)t * HDIM + col0 + wn + cf * 16 + fl, acc[rf][cf][v]);
        }
      }
}

extern "C" void kernel_launch(void* const* d_in, const int* in_sizes, int n_in,
                              void* d_out, int out_size, void* d_ws, size_t ws_size,
                              hipStream_t stream) {
  const float* x   = (const float*)d_in[0];
  const int*   idx = (const int*)d_in[1];
  const float* wts = (const float*)d_in[2];
  const float* Wgu = (const float*)d_in[3];
  const float* Wd  = (const float*)d_in[4];
  float* out = (float*)d_out;

  char* ws = (char*)d_ws;
  int*            cnt = (int*)(ws + 0);
  int*            tok = (int*)(ws + 64);
  float*          wl  = (float*)(ws + 65600);
  int*            inv = (int*)(ws + 131136);
  unsigned short* xe  = (unsigned short*)(ws + 139328);
  unsigned short* hb  = (unsigned short*)(ws + 12722240);

  hipMemsetAsync(cnt, 0, NEXP * sizeof(int), stream);
  hipMemsetAsync(out, 0, (size_t)T_TOK * HDIM * sizeof(float), stream);
  k_gather<<<dim3((T_TOK * TOPK) / 256), 256, 0, stream>>>(idx, wts, cnt, tok, wl, inv);
  k_compact<<<dim3(T_TOK * TOPK), 256, 0, stream>>>(x, inv, xe);
  k_gate_up<<<dim3(NEXP * (IDIM / 64)), 1024, 0, stream>>>(xe, Wgu, cnt, wl, hb);
  k_down<<<dim3(NEXP * (HDIM / 128)), 1024, 0, stream>>>(hb, Wd, cnt, tok, out);
}

// Round 12
// 108.669 us; speedup vs baseline: 2.1594x; 2.1594x over previous
//
#include <hip/hip_runtime.h>
#include <hip/hip_bf16.h>

#define T_TOK 1024
#define TOPK  2
#define NEXP  8
#define HDIM  2048
#define IDIM  768
#define MROW  384   // per-expert row capacity (mean 256, sd ~15)

typedef __attribute__((ext_vector_type(4))) float f32x4;
typedef __attribute__((ext_vector_type(8))) short bf16x8;
typedef __attribute__((ext_vector_type(8))) unsigned short u16x8;
typedef __attribute__((ext_vector_type(8))) __bf16 bfv8;

__device__ __forceinline__ bf16x8 cvt8(f32x4 v0, f32x4 v1) {
  bfv8 r;
#pragma unroll
  for (int j = 0; j < 4; ++j) { r[j] = (__bf16)v0[j]; r[4 + j] = (__bf16)v1[j]; }
  return __builtin_bit_cast(bf16x8, r);
}

// async global->LDS, 16B per lane; LDS dest base must be wave-uniform.
__device__ __forceinline__ void gload_lds16(const void* g, void* l) {
  __builtin_amdgcn_global_load_lds(
      (const __attribute__((address_space(1))) unsigned int*)((unsigned long long)g),
      (__attribute__((address_space(3))) unsigned int*)(unsigned int)(unsigned long long)(l),
      16, 0, 0);
}

// ---------------- workspace layout (bytes) ----------------
// cnt : int[8]                 @ 0
// tok : int[8*2048]            @ 64
// wl  : float[8*2048]          @ 65600
// inv : int[2048]              @ 131136
// xe  : ushort[8*384*2048]     @ 139328   (12.6 MB, expert-compacted bf16 x)
// hb  : ushort[8*384*768]      @ 12722240 (4.7 MB)

__global__ void k_gather(const int* __restrict__ idx, const float* __restrict__ wts,
                         int* __restrict__ cnt, int* __restrict__ tok,
                         float* __restrict__ wl, int* __restrict__ inv) {
  int g = blockIdx.x * 256 + threadIdx.x;   // pid = t*2+k
  int e = idx[g];
  float w = wts[g];
  int pos = atomicAdd(&cnt[e], 1);
  if (pos < 2048) { tok[e * 2048 + pos] = g; wl[e * 2048 + pos] = w; }
  inv[g] = (pos < MROW) ? (e * MROW + pos) : -1;
}

__global__ __launch_bounds__(256) void k_compact(const float* __restrict__ x,
                                                 const int* __restrict__ inv,
                                                 unsigned short* __restrict__ xe) {
  int pid = blockIdx.x;
  int iv = inv[pid];
  if (iv < 0) return;
  const float* src = x + (size_t)(pid >> 1) * HDIM;
  unsigned short* dst = xe + (size_t)iv * HDIM;
  int i = threadIdx.x * 8;
  f32x4 a = *(const f32x4*)(src + i);
  f32x4 b = *(const f32x4*)(src + i + 4);
  *(bf16x8*)(dst + i) = cvt8(a, b);
}

// ================= gate_up =================
// grid 8e x 3mt x 24nb = 576 blocks (~384 active), 256 thr (4 waves, 2x2).
// Tile M=128 (B re-read 2x instead of 4x), N = 32 gate + 32 up cols, K_STEP=64.
// A: global_load_lds (bf16, pre-swizzled src). B: f32 -> reg -> cvt -> swizzled
// ds_write. Double-buffered, 1 __syncthreads per step (R5-proven schedule).
__global__ __launch_bounds__(256) void k_gate_up(
    const unsigned short* __restrict__ xe, const float* __restrict__ Wgu,
    const int* __restrict__ cnt, const float* __restrict__ wl,
    unsigned short* __restrict__ hb)
{
  const int b = blockIdx.x;
  const int e = b & 7;
  const int r = b >> 3;          // 0..71
  const int mt = r % 3;
  const int nb = r / 3;          // 0..23
  const int m0 = mt * 128;
  int cc = cnt[e]; if (cc > MROW) cc = MROW;
  if (m0 >= cc) return;
  const int col0 = nb * 32;

  __shared__ unsigned short sA[2][128 * 64];
  __shared__ unsigned short sB[2][64 * 64];   // rows 0-31 gate, 32-63 up
  __shared__ float sW[128];

  const int tid = threadIdx.x;
  const int lane = tid & 63, wid = tid >> 6;

  if (tid < 128) sW[tid] = (m0 + tid < cc) ? wl[e * 2048 + m0 + tid] : 0.f;

  // A staging: wave covers rows wid*32..wid*32+31; 4 instrs x 1KB (R4-proven)
  const unsigned short* xeE = xe + ((size_t)e * MROW + m0) * HDIM;
  const unsigned short* aSrc[4];
  unsigned int aDstOff[4];
#pragma unroll
  for (int i = 0; i < 4; ++i) {
    int row = wid * 32 + i * 8 + (lane >> 3);
    int csrc = (lane & 7) ^ (row & 7);          // pre-swizzled source chunk
    aSrc[i] = xeE + (size_t)row * HDIM + csrc * 8;
    aDstOff[i] = (unsigned)(wid * 32 + i * 8) * 64;
  }

  // B staging (R5-proven): thread -> row tid>>2 (0..63), floats (tid&3)*16..+15
  const int brow = tid >> 2, cq = (tid & 3);
  const int ocol = (brow < 32) ? (col0 + brow) : (IDIM + col0 + (brow - 32));
  const float* bSrc = Wgu + ((size_t)e * 2 * IDIM + ocol) * HDIM + cq * 16;
  unsigned int bDst[2];
#pragma unroll
  for (int c2 = 0; c2 < 2; ++c2)
    bDst[c2] = (unsigned)(brow * 64 + (((cq * 2 + c2) ^ (brow & 7)) * 8));

  const int fl = lane & 15, q = lane >> 4;
  const int wm = (wid >> 1) * 64, wn = (wid & 1) * 16;

  f32x4 accg[4], accu[4];
#pragma unroll
  for (int rf = 0; rf < 4; ++rf) {
    accg[rf] = f32x4{0.f, 0.f, 0.f, 0.f};
    accu[rf] = f32x4{0.f, 0.f, 0.f, 0.f};
  }

  f32x4 bl[4];

  auto STAGE_ISSUE = [&](int buf, int kt) {
#pragma unroll
    for (int i = 0; i < 4; ++i)
      gload_lds16(aSrc[i] + kt, &sA[buf][aDstOff[i]]);
#pragma unroll
    for (int j = 0; j < 4; ++j)
      bl[j] = *(const f32x4*)(bSrc + kt + j * 4);
  };
  auto STAGE_WRITE = [&](int buf) {
#pragma unroll
    for (int c2 = 0; c2 < 2; ++c2)
      *(bf16x8*)&sB[buf][bDst[c2]] = cvt8(bl[c2 * 2], bl[c2 * 2 + 1]);
  };
  auto COMPUTE = [&](int buf) {
    const unsigned short* A = sA[buf];
    const unsigned short* B = sB[buf];
#pragma unroll
    for (int s = 0; s < 2; ++s) {
      bf16x8 a[4], g2, u2;
#pragma unroll
      for (int rf = 0; rf < 4; ++rf) {
        int rr = wm + rf * 16 + fl;
        a[rf] = *(const bf16x8*)(A + rr * 64 + (((s * 4 + q) ^ (rr & 7)) * 8));
      }
      {
        int rg = wn + fl;
        g2 = *(const bf16x8*)(B + rg * 64 + (((s * 4 + q) ^ (rg & 7)) * 8));
        int ru = 32 + wn + fl;
        u2 = *(const bf16x8*)(B + ru * 64 + (((s * 4 + q) ^ (ru & 7)) * 8));
      }
#pragma unroll
      for (int rf = 0; rf < 4; ++rf) {
        accg[rf] = __builtin_amdgcn_mfma_f32_16x16x32_bf16(a[rf], g2, accg[rf], 0, 0, 0);
        accu[rf] = __builtin_amdgcn_mfma_f32_16x16x32_bf16(a[rf], u2, accu[rf], 0, 0, 0);
      }
    }
  };

  STAGE_ISSUE(0, 0);
  STAGE_WRITE(0);
  __syncthreads();
  int buf = 0;
  for (int kt = 0; kt < HDIM; kt += 64) {
    const int nxt = kt + 64;
    const bool more = nxt < HDIM;
    if (more) STAGE_ISSUE(buf ^ 1, nxt);
    COMPUTE(buf);
    if (more) STAGE_WRITE(buf ^ 1);
    __syncthreads();
    buf ^= 1;
  }

  unsigned short* hbE = hb + (size_t)e * MROW * IDIM;
  const int q4 = q * 4;
#pragma unroll
  for (int rf = 0; rf < 4; ++rf)
#pragma unroll
    for (int v = 0; v < 4; ++v) {
      int rowl = wm + rf * 16 + q4 + v;
      if (m0 + rowl < cc) {
        float g = accg[rf][v], u = accu[rf][v];
        float s = g / (1.f + __expf(-g));
        float h = s * u * sW[rowl];
        hbE[(size_t)(m0 + rowl) * IDIM + col0 + wn + fl] =
            __builtin_bit_cast(unsigned short, (__bf16)h);
      }
    }
}

// ================= down (R8-proven, unchanged) =================
// grid 8e x 6mt x 32nb = 1536 blocks, 256 thr. Tile M=64, N=64, K=768.
__global__ __launch_bounds__(256, 3) void k_down(
    const unsigned short* __restrict__ hb, const float* __restrict__ Wd,
    const int* __restrict__ cnt, const int* __restrict__ tok,
    float* __restrict__ out)
{
  const int b = blockIdx.x;
  const int e = b & 7;
  const int r = b >> 3;          // 0..191
  const int mt = r % 6;
  const int nb = r / 6;          // 0..31
  const int m0 = mt * 64;
  int cc = cnt[e]; if (cc > MROW) cc = MROW;
  if (m0 >= cc) return;
  const int col0 = nb * 64;

  __shared__ unsigned short sA[3 * 4096];
  __shared__ unsigned short sB[3 * 4096];
  __shared__ int sTok[64];

  const int tid = threadIdx.x;
  const int lane = tid & 63, wid = tid >> 6;
  if (tid < 64) sTok[tid] = (m0 + tid < cc) ? (tok[e * 2048 + m0 + tid] >> 1) : 0;

  const unsigned short* hbE = hb + ((size_t)e * MROW + m0) * IDIM;
  const unsigned short* aSrc[2];
  unsigned int aDstOff[2];
#pragma unroll
  for (int i = 0; i < 2; ++i) {
    int row = wid * 16 + i * 8 + (lane >> 3);
    int csrc = (lane & 7) ^ (row & 7);
    aSrc[i] = hbE + (size_t)row * IDIM + csrc * 8;
    aDstOff[i] = (unsigned)(wid * 16 + i * 8) * 64;
  }

  const int brow = tid >> 2, cq = (tid & 3);
  const float* bSrc = Wd + ((size_t)e * HDIM + col0 + brow) * IDIM + cq * 16;
  unsigned int bDst[2];
#pragma unroll
  for (int c2 = 0; c2 < 2; ++c2)
    bDst[c2] = (unsigned)(brow * 64 + (((cq * 2 + c2) ^ (brow & 7)) * 8));

  const int fl = lane & 15, q = lane >> 4;
  const int wm = (wid >> 1) * 32, wn = (wid & 1) * 32;

  f32x4 acc[2][2];
#pragma unroll
  for (int mf = 0; mf < 2; ++mf)
#pragma unroll
    for (int nf = 0; nf < 2; ++nf) acc[mf][nf] = f32x4{0.f, 0.f, 0.f, 0.f};

  f32x4 blA[4], blB[4];
  const int NS = IDIM / 64;

  auto COMPUTE = [&](int bo) {
    const unsigned short* A = sA + bo;
    const unsigned short* B = sB + bo;
#pragma unroll
    for (int s = 0; s < 2; ++s) {
      bf16x8 a[2], bb[2];
#pragma unroll
      for (int mf = 0; mf < 2; ++mf) {
        int rr = wm + mf * 16 + fl;
        a[mf] = *(const bf16x8*)(A + rr * 64 + (((s * 4 + q) ^ (rr & 7)) * 8));
      }
#pragma unroll
      for (int nf = 0; nf < 2; ++nf) {
        int rn = wn + nf * 16 + fl;
        bb[nf] = *(const bf16x8*)(B + rn * 64 + (((s * 4 + q) ^ (rn & 7)) * 8));
      }
#pragma unroll
      for (int mf = 0; mf < 2; ++mf)
#pragma unroll
        for (int nf = 0; nf < 2; ++nf)
          acc[mf][nf] = __builtin_amdgcn_mfma_f32_16x16x32_bf16(a[mf], bb[nf], acc[mf][nf], 0, 0, 0);
    }
  };

  auto ITER = [&](int ks, f32x4 (&blR)[4], f32x4 (&blW)[4],
                  int oC, int oN, int oNN) {
    const bool nL = (ks + 2) < NS;
    const bool nW = (ks + 1) < NS;
    if (nL) {
#pragma unroll
      for (int i = 0; i < 2; ++i)
        gload_lds16(aSrc[i] + (ks + 2) * 64, &sA[oNN + aDstOff[i]]);
#pragma unroll
      for (int j = 0; j < 4; ++j)
        blW[j] = *(const f32x4*)(bSrc + (ks + 2) * 64 + j * 4);
    }
    if (nW) {
#pragma unroll
      for (int c2 = 0; c2 < 2; ++c2)
        *(bf16x8*)&sB[oN + bDst[c2]] = cvt8(blR[c2 * 2], blR[c2 * 2 + 1]);
    }
    COMPUTE(oC);
    if (nW) {
      if (nL) { asm volatile("s_waitcnt vmcnt(6) lgkmcnt(0)" ::: "memory"); }
      else    { asm volatile("s_waitcnt vmcnt(0) lgkmcnt(0)" ::: "memory"); }
      __builtin_amdgcn_sched_barrier(0);
      __builtin_amdgcn_s_barrier();
      __builtin_amdgcn_sched_barrier(0);
    }
  };

#pragma unroll
  for (int i = 0; i < 2; ++i) gload_lds16(aSrc[i], &sA[aDstOff[i]]);
#pragma unroll
  for (int j = 0; j < 4; ++j) blA[j] = *(const f32x4*)(bSrc + j * 4);
#pragma unroll
  for (int i = 0; i < 2; ++i) gload_lds16(aSrc[i] + 64, &sA[4096 + aDstOff[i]]);
#pragma unroll
  for (int j = 0; j < 4; ++j) blB[j] = *(const f32x4*)(bSrc + 64 + j * 4);
#pragma unroll
  for (int c2 = 0; c2 < 2; ++c2)
    *(bf16x8*)&sB[bDst[c2]] = cvt8(blA[c2 * 2], blA[c2 * 2 + 1]);
  asm volatile("s_waitcnt vmcnt(6) lgkmcnt(0)" ::: "memory");
  __builtin_amdgcn_sched_barrier(0);
  __builtin_amdgcn_s_barrier();
  __builtin_amdgcn_sched_barrier(0);

  int oC = 0, oN = 4096, oNN = 8192;
  for (int ks = 0; ks < NS; ks += 2) {
    ITER(ks, blB, blA, oC, oN, oNN);
    int t = oC; oC = oN; oN = oNN; oNN = t;
    ITER(ks + 1, blA, blB, oC, oN, oNN);
    t = oC; oC = oN; oN = oNN; oNN = t;
  }

  const int q4 = q * 4;
#pragma unroll
  for (int mf = 0; mf < 2; ++mf)
#pragma unroll
    for (int nf = 0; nf < 2; ++nf)
#pragma unroll
      for (int v = 0; v < 4; ++v) {
        int rowl = wm + mf * 16 + q4 + v;
        if (m0 + rowl < cc) {
          int t = sTok[rowl];
          atomicAdd(out + (size_t)t * HDIM + col0 + wn + nf * 16 + fl, acc[mf][nf][v]);
        }
      }
}

extern "C" void kernel_launch(void* const* d_in, const int* in_sizes, int n_in,
                              void* d_out, int out_size, void* d_ws, size_t ws_size,
                              hipStream_t stream) {
  const float* x   = (const float*)d_in[0];
  const int*   idx = (const int*)d_in[1];
  const float* wts = (const float*)d_in[2];
  const float* Wgu = (const float*)d_in[3];
  const float* Wd  = (const float*)d_in[4];
  float* out = (float*)d_out;

  char* ws = (char*)d_ws;
  int*            cnt = (int*)(ws + 0);
  int*            tok = (int*)(ws + 64);
  float*          wl  = (float*)(ws + 65600);
  int*            inv = (int*)(ws + 131136);
  unsigned short* xe  = (unsigned short*)(ws + 139328);
  unsigned short* hb  = (unsigned short*)(ws + 12722240);

  hipMemsetAsync(cnt, 0, NEXP * sizeof(int), stream);
  hipMemsetAsync(out, 0, (size_t)T_TOK * HDIM * sizeof(float), stream);
  k_gather<<<dim3((T_TOK * TOPK) / 256), 256, 0, stream>>>(idx, wts, cnt, tok, wl, inv);
  k_compact<<<dim3(T_TOK * TOPK), 256, 0, stream>>>(x, inv, xe);
  k_gate_up<<<dim3(NEXP * 3 * 24), 256, 0, stream>>>(xe, Wgu, cnt, wl, hb);
  k_down<<<dim3(NEXP * 6 * 32), 256, 0, stream>>>(hb, Wd, cnt, tok, out);
}